// Round 11
// baseline (83.269 us; speedup 1.0000x reference)
//
#include <hip/hip_runtime.h>
#include <math.h>

#define N 1024
#define H 128
#define CLIPV 10.0f

#define TI 64
#define TJ 64
#define LDSP 132           // padded row stride: 132 % 32 = 4 -> 4-bank rotation/row
#define NBLK ((N / TI) * (N / TJ))   // 256 pair-blocks

// ---------------------------------------------------------------------------
// Kernel A: A[j][h]  = z_c @ w1[:128]           (j-side operand)
//           Cb[i][h] = z_d @ w1[128:] + b1      (i-side operand, bias folded)
// Delta vs R10: 512-thread blocks (8 rows, 2 rows/thread) -> 8 waves/CU
// instead of 4 on this latency-bound loop. grid (128, 2), 256 blocks.
// ---------------------------------------------------------------------------
__global__ __launch_bounds__(512) void k_gemm(const float* __restrict__ z_c,
                                              const float* __restrict__ z_d,
                                              const float* __restrict__ w1,
                                              const float* __restrict__ b1,
                                              float* __restrict__ A,
                                              float* __restrict__ Cb) {
    const int which = blockIdx.y;            // 0 -> A, 1 -> Cb
    const int n0 = blockIdx.x * 8;
    const int tid = threadIdx.x;
    const float* __restrict__ z = which ? z_d : z_c;
    const float* __restrict__ w = w1 + which * (H * H);

    __shared__ float zs[8][H];
    if (tid < 256) {
        const int c4 = (tid & 31) * 4;
        const int r  = tid >> 5;             // 0..7
        *(float4*)&zs[r][c4] = *(const float4*)&z[(n0 + r) * H + c4];
    }
    __syncthreads();

    const int h = tid & 127;
    const int g = tid >> 7;                  // row-group 0..3 (rows 2g, 2g+1)

    float a0 = 0.f, a1 = 0.f;
    #pragma unroll 8
    for (int k = 0; k < H; ++k) {
        const float wv = w[k * H + h];
        a0 = fmaf(zs[2 * g + 0][k], wv, a0);
        a1 = fmaf(zs[2 * g + 1][k], wv, a1);
    }
    const float bias = which ? b1[h] : 0.0f;
    float* __restrict__ dst = which ? Cb : A;
    dst[(n0 + 2 * g + 0) * H + h] = a0 + bias;
    dst[(n0 + 2 * g + 1) * H + h] = a1 + bias;
}

// ---------------------------------------------------------------------------
// Kernel B: pairwise T1 = sum_h relu(A[j][h]+Cb[i][h])*w2[h] + b2
// Delta vs R10: 4x8 register blocking, 4-way h-split. 64x64 tile, 512
// threads = 4 h-quarters x 128 compute threads; each computes 4i x 8j.
// Per iter: 12 ds_read_b128 feed 32 outputs (1.5 B per madd-triple vs 2.0
// at 4x4) -> LDS-pipe ~4.2 us vs 5.8, VALU unchanged. (512,1) uncapped.
// Combine scratch: plane layout, sequential float4 per lane (conflict-free).
// ---------------------------------------------------------------------------
__global__ __launch_bounds__(512, 1) void k_pair(const float* __restrict__ A,
                                                 const float* __restrict__ Cb,
                                                 const float* __restrict__ w2,
                                                 const float* __restrict__ b2p,
                                                 float* __restrict__ pdiag,
                                                 float* __restrict__ psume) {
    __shared__ float Ash[TJ][LDSP];          // 8448 floats
    __shared__ float Csh[TI][LDSP];          // 8448 floats
    __shared__ float w2s[H];
    __shared__ float red[16];

    const int tid = threadIdx.x;
    const int i0 = blockIdx.x * TI;
    const int j0 = blockIdx.y * TJ;

    // ---- staging: 512 threads, 128 rows (64 A + 64 C) x 32 float4 cols ----
    {
        const int c4 = (tid & 31) * 4;
        const int r  = tid >> 5;             // 0..15
        #pragma unroll
        for (int rr = 0; rr < 4; ++rr) {
            const int row = r + rr * 16;     // 0..63
            *(float4*)&Ash[row][c4] = *(const float4*)&A[(j0 + row) * H + c4];
            *(float4*)&Csh[row][c4] = *(const float4*)&Cb[(i0 + row) * H + c4];
        }
        if (tid < 32) *(float4*)&w2s[tid * 4] = *(const float4*)&w2[tid * 4];
    }
    __syncthreads();

    const int t128 = tid & 127;
    const int hh = tid >> 7;                 // h-quarter 0..3 (wave-pair aligned)
    const int tj = t128 & 7;                 // j group (8): j = j0 + tj + dj*8
    const int ti = t128 >> 3;                // i group (16): i = i0 + ti + di*16

    float s[4][8];
    #pragma unroll
    for (int di = 0; di < 4; ++di)
        #pragma unroll
        for (int dj = 0; dj < 8; ++dj) s[di][dj] = 0.f;

    const int h4base = hh * 8;
    #pragma unroll 2
    for (int h4i = 0; h4i < 8; ++h4i) {
        const int h4 = h4base + h4i;
        const float4 w4 = *(const float4*)&w2s[h4 * 4];
        float4 cf[4], af[8];
        #pragma unroll
        for (int d = 0; d < 4; ++d)
            cf[d] = *(const float4*)&Csh[ti + d * 16][h4 * 4];
        #pragma unroll
        for (int e = 0; e < 8; ++e)
            af[e] = *(const float4*)&Ash[tj + e * 8][h4 * 4];
        #pragma unroll
        for (int q = 0; q < 4; ++q) {
            const float wv = ((const float*)&w4)[q];
            #pragma unroll
            for (int di = 0; di < 4; ++di) {
                const float cv = ((const float*)&cf[di])[q];
                #pragma unroll
                for (int dj = 0; dj < 8; ++dj) {
                    const float t = fmaxf(cv + ((const float*)&af[dj])[q], 0.f);
                    s[di][dj] = fmaf(t, wv, s[di][dj]);
                }
            }
        }
    }

    // ---- combine 4 h-quarters via LDS planes (sequential float4 = free) ---
    // plane p = di*2 + half (half: dj 0..3 vs 4..7); 8 planes x 128 x float4
    // = 4096 floats per quarter. scr1 in Ash (4096<=8448), scr2/scr3 in Csh.
    __syncthreads();                         // compute done, safe to overwrite
    float* scr1 = &Ash[0][0];
    float* scr2 = &Csh[0][0];
    float* scr3 = &Csh[0][0] + 4224;         // 4224+4096 = 8320 <= 8448
    if (hh != 0) {
        float* dst = (hh == 1) ? scr1 : (hh == 2) ? scr2 : scr3;
        #pragma unroll
        for (int di = 0; di < 4; ++di) {
            float4 lo, hi;
            lo.x = s[di][0]; lo.y = s[di][1]; lo.z = s[di][2]; lo.w = s[di][3];
            hi.x = s[di][4]; hi.y = s[di][5]; hi.z = s[di][6]; hi.w = s[di][7];
            *(float4*)&dst[((di * 2 + 0) * 128 + t128) * 4] = lo;
            *(float4*)&dst[((di * 2 + 1) * 128 + t128) * 4] = hi;
        }
    }
    __syncthreads();

    float diag = 0.f, sume = 0.f;
    if (hh == 0) {
        const float b2 = b2p[0];
        #pragma unroll
        for (int di = 0; di < 4; ++di) {
            #pragma unroll
            for (int half = 0; half < 2; ++half) {
                const int p = di * 2 + half;
                const float4 p1 = *(const float4*)&scr1[(p * 128 + t128) * 4];
                const float4 p2 = *(const float4*)&scr2[(p * 128 + t128) * 4];
                const float4 p3 = *(const float4*)&scr3[(p * 128 + t128) * 4];
                #pragma unroll
                for (int q = 0; q < 4; ++q) {
                    const int dj = half * 4 + q;
                    const float v = s[di][dj] + ((const float*)&p1)[q]
                                  + ((const float*)&p2)[q]
                                  + ((const float*)&p3)[q] + b2;
                    const int i = i0 + ti + di * 16;
                    const int j = j0 + tj + dj * 8;
                    if (i == j) {
                        diag += v;
                    } else {
                        const float vc = fminf(fmaxf(v, -CLIPV), CLIPV);
                        sume += __expf(vc - CLIPV);
                    }
                }
            }
        }
    }

    // ---- block reduction: wave shuffle, then LDS across 8 waves ----
    #pragma unroll
    for (int off = 32; off; off >>= 1) {
        diag += __shfl_down(diag, off);
        sume += __shfl_down(sume, off);
    }
    if ((tid & 63) == 0) { red[tid >> 6] = diag; red[8 + (tid >> 6)] = sume; }
    __syncthreads();
    if (tid == 0) {
        float d = 0.f, e = 0.f;
        #pragma unroll
        for (int k = 0; k < 8; ++k) { d += red[k]; e += red[8 + k]; }
        const int bid = blockIdx.y * gridDim.x + blockIdx.x;
        pdiag[bid] = d;
        psume[bid] = e;
    }
}

// ---------------------------------------------------------------------------
// Kernel C: reduce 256 block-partials (f64) and finalize scalar
// ---------------------------------------------------------------------------
__global__ __launch_bounds__(256) void k_final(const float* __restrict__ pdiag,
                                               const float* __restrict__ psume,
                                               float* __restrict__ out) {
    const int tid = threadIdx.x;
    double d = (double)pdiag[tid];
    double e = (double)psume[tid];
    #pragma unroll
    for (int off = 32; off; off >>= 1) {
        d += __shfl_down(d, off);
        e += __shfl_down(e, off);
    }
    __shared__ double rd[4], re[4];
    if ((tid & 63) == 0) { rd[tid >> 6] = d; re[tid >> 6] = e; }
    __syncthreads();
    if (tid == 0) {
        const double dt = rd[0] + rd[1] + rd[2] + rd[3];
        const double et = re[0] + re[1] + re[2] + re[3];
        const double T0  = dt / (double)N;
        const double lme = log(et) + (double)CLIPV
                         - log((double)N * ((double)N - 1.0));
        out[0] = (float)(T0 - lme);
    }
}

extern "C" void kernel_launch(void* const* d_in, const int* in_sizes, int n_in,
                              void* d_out, int out_size, void* d_ws, size_t ws_size,
                              hipStream_t stream) {
    const float* z_c = (const float*)d_in[0];
    const float* z_d = (const float*)d_in[1];
    const float* w1  = (const float*)d_in[2];
    const float* b1  = (const float*)d_in[3];
    const float* w2  = (const float*)d_in[4];
    const float* b2  = (const float*)d_in[5];

    float* A     = (float*)d_ws;             // N*H
    float* Cb    = A + N * H;                // N*H
    float* pdiag = Cb + N * H;               // NBLK
    float* psume = pdiag + NBLK;             // NBLK

    k_gemm<<<dim3(N / 8, 2), 512, 0, stream>>>(z_c, z_d, w1, b1, A, Cb);
    k_pair<<<dim3(N / TI, N / TJ), 512, 0, stream>>>(A, Cb, w2, b2, pdiag, psume);
    k_final<<<1, 256, 0, stream>>>(pdiag, psume, (float*)d_out);
}

// Round 12
// 83.139 us; speedup vs baseline: 1.0016x; 1.0016x over previous
//
#include <hip/hip_runtime.h>
#include <math.h>

#define N 1024
#define H 128
#define CLIPV 10.0f

#define TI 64
#define TJ 64
#define LDSP 132           // padded row stride: 132 % 32 = 4 -> 4-bank rotation/row
#define NBLK ((N / TI) * (N / TJ))   // 256 pair-blocks

// ---------------------------------------------------------------------------
// Kernel A: A[j][h]  = z_c @ w1[:128]           (j-side operand)
//           Cb[i][h] = z_d @ w1[128:] + b1      (i-side operand, bias folded)
// grid (N/8, 2), block 256. 8 rows/block staged in LDS.
// ---------------------------------------------------------------------------
__global__ __launch_bounds__(256) void k_gemm(const float* __restrict__ z_c,
                                              const float* __restrict__ z_d,
                                              const float* __restrict__ w1,
                                              const float* __restrict__ b1,
                                              float* __restrict__ A,
                                              float* __restrict__ Cb) {
    const int which = blockIdx.y;            // 0 -> A, 1 -> Cb
    const int n0 = blockIdx.x * 8;
    const int tid = threadIdx.x;
    const float* __restrict__ z = which ? z_d : z_c;
    const float* __restrict__ w = w1 + which * (H * H);

    __shared__ float zs[8][H];
    {
        const int c4 = (tid & 31) * 4;
        const int r  = tid >> 5;             // 0..7
        *(float4*)&zs[r][c4] = *(const float4*)&z[(n0 + r) * H + c4];
    }
    __syncthreads();

    const int h = tid & 127;
    const int g = tid >> 7;                  // row-group 0/1 (rows g*4..g*4+3)

    float a0 = 0.f, a1 = 0.f, a2 = 0.f, a3 = 0.f;
    #pragma unroll 8
    for (int k = 0; k < H; ++k) {
        const float wv = w[k * H + h];
        a0 = fmaf(zs[g * 4 + 0][k], wv, a0);
        a1 = fmaf(zs[g * 4 + 1][k], wv, a1);
        a2 = fmaf(zs[g * 4 + 2][k], wv, a2);
        a3 = fmaf(zs[g * 4 + 3][k], wv, a3);
    }
    const float bias = which ? b1[h] : 0.0f;
    float* __restrict__ dst = which ? Cb : A;
    dst[(n0 + g * 4 + 0) * H + h] = a0 + bias;
    dst[(n0 + g * 4 + 1) * H + h] = a1 + bias;
    dst[(n0 + g * 4 + 2) * H + h] = a2 + bias;
    dst[(n0 + g * 4 + 3) * H + h] = a3 + bias;
}

// ---------------------------------------------------------------------------
// Kernel B: pairwise T1 = sum_h relu(A[j][h]+Cb[i][h])*w2[h] + b2
// 64x64 tile per block, 512 threads = 2 h-halves x 256 compute threads.
// Proven config (82.8/82.7 across sessions). Falsified levers, do not retry:
//   (512,4) VGPR cap (R5/R8, ~neutral-negative; grid=256=1 block/CU anyway),
//   atomic+fence merged finalize (R9, +9 us),
//   4x8 blocking + 4-way h-split (R11, neutral).
// ---------------------------------------------------------------------------
__global__ __launch_bounds__(512, 1) void k_pair(const float* __restrict__ A,
                                                 const float* __restrict__ Cb,
                                                 const float* __restrict__ w2,
                                                 const float* __restrict__ b2p,
                                                 float* __restrict__ pdiag,
                                                 float* __restrict__ psume) {
    __shared__ float Ash[TJ][LDSP];
    __shared__ float Csh[TI][LDSP];
    __shared__ float w2s[H];
    __shared__ float red[16];

    const int tid = threadIdx.x;
    const int i0 = blockIdx.x * TI;
    const int j0 = blockIdx.y * TJ;

    // ---- staging: 512 threads, 128 rows (64 A + 64 C) x 32 float4 cols ----
    {
        const int c4 = (tid & 31) * 4;
        const int r  = tid >> 5;             // 0..15
        #pragma unroll
        for (int rr = 0; rr < 4; ++rr) {
            const int row = r + rr * 16;     // 0..63
            *(float4*)&Ash[row][c4] = *(const float4*)&A[(j0 + row) * H + c4];
            *(float4*)&Csh[row][c4] = *(const float4*)&Cb[(i0 + row) * H + c4];
        }
        if (tid < 32) *(float4*)&w2s[tid * 4] = *(const float4*)&w2[tid * 4];
    }
    __syncthreads();

    const int t256 = tid & 255;
    const int tj = t256 & 15;                // j group (16)
    const int ti = t256 >> 4;                // i group (16)
    const int hh = tid >> 8;                 // h-half 0/1

    float s[4][4] = {{0.f,0.f,0.f,0.f},{0.f,0.f,0.f,0.f},
                     {0.f,0.f,0.f,0.f},{0.f,0.f,0.f,0.f}};

    const int h4base = hh * 16;
    #pragma unroll 4
    for (int h4i = 0; h4i < 16; ++h4i) {
        const int h4 = h4base + h4i;
        const float4 w4 = *(const float4*)&w2s[h4 * 4];
        float4 cf[4], af[4];
        #pragma unroll
        for (int d = 0; d < 4; ++d) {
            cf[d] = *(const float4*)&Csh[ti + d * 16][h4 * 4];
            af[d] = *(const float4*)&Ash[tj + d * 16][h4 * 4];
        }
        #pragma unroll
        for (int q = 0; q < 4; ++q) {
            const float wv = ((const float*)&w4)[q];
            #pragma unroll
            for (int di = 0; di < 4; ++di) {
                const float cv = ((const float*)&cf[di])[q];
                #pragma unroll
                for (int dj = 0; dj < 4; ++dj) {
                    const float t = fmaxf(cv + ((const float*)&af[dj])[q], 0.f);
                    s[di][dj] = fmaf(t, wv, s[di][dj]);
                }
            }
        }
    }

    // ---- combine h-halves (reuse Ash as scratch; stride 20 -> <=2-way) ----
    float* comb = &Ash[0][0];                // 256*20 = 5120 <= 64*132
    __syncthreads();
    if (hh == 1) {
        #pragma unroll
        for (int di = 0; di < 4; ++di) {
            float4 v4;
            v4.x = s[di][0]; v4.y = s[di][1]; v4.z = s[di][2]; v4.w = s[di][3];
            *(float4*)&comb[t256 * 20 + di * 4] = v4;
        }
    }
    __syncthreads();

    float diag = 0.f, sume = 0.f;
    if (hh == 0) {
        const float b2 = b2p[0];
        #pragma unroll
        for (int di = 0; di < 4; ++di) {
            #pragma unroll
            for (int dj = 0; dj < 4; ++dj) {
                const float v = s[di][dj] + comb[t256 * 20 + di * 4 + dj] + b2;
                const int i = i0 + ti + di * 16;
                const int j = j0 + tj + dj * 16;
                if (i == j) {
                    diag += v;
                } else {
                    const float vc = fminf(fmaxf(v, -CLIPV), CLIPV);
                    sume += __expf(vc - CLIPV);
                }
            }
        }
    }

    // ---- block reduction: wave shuffle, then LDS across 8 waves ----
    #pragma unroll
    for (int off = 32; off; off >>= 1) {
        diag += __shfl_down(diag, off);
        sume += __shfl_down(sume, off);
    }
    if ((tid & 63) == 0) { red[tid >> 6] = diag; red[8 + (tid >> 6)] = sume; }
    __syncthreads();
    if (tid == 0) {
        float d = 0.f, e = 0.f;
        #pragma unroll
        for (int k = 0; k < 8; ++k) { d += red[k]; e += red[8 + k]; }
        const int bid = blockIdx.y * gridDim.x + blockIdx.x;
        pdiag[bid] = d;
        psume[bid] = e;
    }
}

// ---------------------------------------------------------------------------
// Kernel C: reduce 256 block-partials (f64) and finalize scalar
// ---------------------------------------------------------------------------
__global__ __launch_bounds__(256) void k_final(const float* __restrict__ pdiag,
                                               const float* __restrict__ psume,
                                               float* __restrict__ out) {
    const int tid = threadIdx.x;
    double d = (double)pdiag[tid];
    double e = (double)psume[tid];
    #pragma unroll
    for (int off = 32; off; off >>= 1) {
        d += __shfl_down(d, off);
        e += __shfl_down(e, off);
    }
    __shared__ double rd[4], re[4];
    if ((tid & 63) == 0) { rd[tid >> 6] = d; re[tid >> 6] = e; }
    __syncthreads();
    if (tid == 0) {
        const double dt = rd[0] + rd[1] + rd[2] + rd[3];
        const double et = re[0] + re[1] + re[2] + re[3];
        const double T0  = dt / (double)N;
        const double lme = log(et) + (double)CLIPV
                         - log((double)N * ((double)N - 1.0));
        out[0] = (float)(T0 - lme);
    }
}

extern "C" void kernel_launch(void* const* d_in, const int* in_sizes, int n_in,
                              void* d_out, int out_size, void* d_ws, size_t ws_size,
                              hipStream_t stream) {
    const float* z_c = (const float*)d_in[0];
    const float* z_d = (const float*)d_in[1];
    const float* w1  = (const float*)d_in[2];
    const float* b1  = (const float*)d_in[3];
    const float* w2  = (const float*)d_in[4];
    const float* b2  = (const float*)d_in[5];

    float* A     = (float*)d_ws;             // N*H
    float* Cb    = A + N * H;                // N*H
    float* pdiag = Cb + N * H;               // NBLK
    float* psume = pdiag + NBLK;             // NBLK

    k_gemm<<<dim3(N / 8, 2), 256, 0, stream>>>(z_c, z_d, w1, b1, A, Cb);
    k_pair<<<dim3(N / TI, N / TJ), 512, 0, stream>>>(A, Cb, w2, b2, pdiag, psume);
    k_final<<<1, 256, 0, stream>>>(pdiag, psume, (float*)d_out);
}